// Round 2
// baseline (683.019 us; speedup 1.0000x reference)
//
#include <hip/hip_runtime.h>
#include <hip/hip_bf16.h>

#define NB 16          // batches
#define NN 1024        // keypoints per side
#define NP 1025        // NN+1 (dustbin)
#define ND 24          // descriptor dim
#define N_ITERS 20

#define NORM_C  (-7.6246189861593985f)   // -log(2048)
#define LOGN_C  ( 6.9314718055994531f)   // log(1024)

// ---------------------------------------------------------------------------
// scores[b][i][j] = (1/sqrt(24)) * sum_d dsc0[b][d][i] * dsc1[b][d][j]
// written as f32 into C (the couplings / output buffer), i,j < 1024
// ---------------------------------------------------------------------------
__global__ __launch_bounds__(256) void scores_kernel(
    const float* __restrict__ d0, const float* __restrict__ d1,
    float* __restrict__ C)
{
  __shared__ float As[ND][64];
  __shared__ float Bs[ND][64];
  const int b  = blockIdx.z;
  const int n0 = blockIdx.y * 64;   // i tile
  const int m0 = blockIdx.x * 64;   // j tile
  const int tid = threadIdx.x;
  const float* pa = d0 + b * ND * NN;
  const float* pb = d1 + b * ND * NN;
  for (int e = tid; e < ND * 64; e += 256) {
    int dd = e >> 6, cc = e & 63;
    As[dd][cc] = pa[dd * NN + n0 + cc];
    Bs[dd][cc] = pb[dd * NN + m0 + cc];
  }
  __syncthreads();
  const int tx = tid & 15;   // j sub-tile
  const int ty = tid >> 4;   // i sub-tile
  float acc[4][4] = {};
  #pragma unroll
  for (int dd = 0; dd < ND; ++dd) {
    float a[4], bb[4];
    #pragma unroll
    for (int r = 0; r < 4; ++r) a[r]  = As[dd][ty * 4 + r];
    #pragma unroll
    for (int c = 0; c < 4; ++c) bb[c] = Bs[dd][tx * 4 + c];
    #pragma unroll
    for (int r = 0; r < 4; ++r)
      #pragma unroll
      for (int c = 0; c < 4; ++c)
        acc[r][c] = fmaf(a[r], bb[c], acc[r][c]);
  }
  const float sc = 0.20412414523193154f;  // 1/sqrt(24)
  #pragma unroll
  for (int r = 0; r < 4; ++r) {
    int i = n0 + ty * 4 + r;
    size_t base = ((size_t)b * NP + i) * NP + m0 + tx * 4;
    #pragma unroll
    for (int c = 0; c < 4; ++c)
      C[base + c] = acc[r][c] * sc;
  }
}

// ---------------------------------------------------------------------------
// dustbin row/col = alpha; v = 0
// ---------------------------------------------------------------------------
__global__ __launch_bounds__(256) void init_kernel(
    float* __restrict__ C, float* __restrict__ v,
    const float* __restrict__ alpha_p)
{
  const float alpha = *alpha_p;
  int idx = blockIdx.x * 256 + threadIdx.x;
  if (idx >= NB * NP) return;
  int b = idx / NP, x = idx - b * NP;
  C[((size_t)b * NP + NN) * NP + x] = alpha;  // dustbin row
  C[((size_t)b * NP + x) * NP + NN] = alpha;  // dustbin col
  v[idx] = 0.f;
}

// ---------------------------------------------------------------------------
// u[b][i] = log_mu[i] - log( sum_j exp( C[b][i][j] + v[b][j] ) )
// one wave per row; max-free LSE (t is bounded ~[-30, +8] for this problem)
// ---------------------------------------------------------------------------
__global__ __launch_bounds__(256) void row_kernel(
    const float* __restrict__ C,
    const float* __restrict__ v, float* __restrict__ u)
{
  const int wid  = (blockIdx.x * 256 + threadIdx.x) >> 6;  // global wave id = row
  const int lane = threadIdx.x & 63;
  const int b = wid / NP;
  const int i = wid - b * NP;
  const float* crow = C + ((size_t)b * NP + i) * NP;
  const float* vb = v + b * NP;
  float s = 0.f;
  #pragma unroll
  for (int k = 0; k < 17; ++k) {
    int j = k * 64 + lane;
    if (j < NP)
      s += __expf(crow[j] + vb[j]);
  }
  #pragma unroll
  for (int off = 32; off; off >>= 1)
    s += __shfl_xor(s, off, 64);
  if (lane == 0) {
    float log_mu = NORM_C + (i == NN ? LOGN_C : 0.f);
    u[b * NP + i] = log_mu - __logf(s);
  }
}

// ---------------------------------------------------------------------------
// v[b][j] = log_nu[j] - log( sum_i exp( C[b][i][j] + u[b][i] ) )
// block: 32 cols x 8 row-chunks; LDS combine
// ---------------------------------------------------------------------------
__global__ __launch_bounds__(256) void col_kernel(
    const float* __restrict__ C,
    const float* __restrict__ u, float* __restrict__ v)
{
  const int b  = blockIdx.y;
  const int tx = threadIdx.x & 31;
  const int ty = threadIdx.x >> 5;  // 0..7
  const int j  = blockIdx.x * 32 + tx;
  const bool valid = (j < NP);
  const float* cb = C + (size_t)b * NP * NP;
  const float* ub = u + b * NP;
  float s = 0.f;
  if (valid) {
    #pragma unroll 4
    for (int i = ty; i < NP; i += 8)
      s += __expf(cb[(size_t)i * NP + j] + ub[i]);
  }
  __shared__ float ss[8][32];
  ss[ty][tx] = s;
  __syncthreads();
  if (ty == 0 && valid) {
    #pragma unroll
    for (int r = 1; r < 8; ++r)
      s += ss[r][tx];
    float log_nu = NORM_C + (j == NN ? LOGN_C : 0.f);
    v[b * NP + j] = log_nu - __logf(s);
  }
}

// ---------------------------------------------------------------------------
// Z = C + u + v - norm   (in place on C, f32)
// ---------------------------------------------------------------------------
__global__ __launch_bounds__(256) void final_kernel(
    float* __restrict__ C,
    const float* __restrict__ u, const float* __restrict__ v)
{
  int idx = blockIdx.x * 256 + threadIdx.x;
  const int total = NB * NP * NP;
  if (idx >= total) return;
  int b   = idx / (NP * NP);
  int rem = idx - b * (NP * NP);
  int i   = rem / NP;
  int j   = rem - i * NP;
  C[idx] = C[idx] + u[b * NP + i] + v[b * NP + j] - NORM_C;
}

extern "C" void kernel_launch(void* const* d_in, const int* in_sizes, int n_in,
                              void* d_out, int out_size, void* d_ws, size_t ws_size,
                              hipStream_t stream) {
  const float* d0    = (const float*)d_in[0];
  const float* d1    = (const float*)d_in[1];
  const float* alpha = (const float*)d_in[2];
  float* C = (float*)d_out;            // [NB][NP][NP] f32 couplings -> Z
  float* v = (float*)d_ws;             // [NB][NP]
  float* u = v + NB * NP;              // [NB][NP]

  scores_kernel<<<dim3(NN / 64, NN / 64, NB), 256, 0, stream>>>(d0, d1, C);
  init_kernel<<<(NB * NP + 255) / 256, 256, 0, stream>>>(C, v, alpha);

  for (int it = 0; it < N_ITERS; ++it) {
    row_kernel<<<(NB * NP) / 4, 256, 0, stream>>>(C, v, u);            // 4100 blocks
    col_kernel<<<dim3((NP + 31) / 32, NB), 256, 0, stream>>>(C, u, v); // 33 x 16
  }

  final_kernel<<<(NB * NP * NP + 255) / 256, 256, 0, stream>>>(C, u, v);
}

// Round 4
// 276.060 us; speedup vs baseline: 2.4742x; 2.4742x over previous
//
#include <hip/hip_runtime.h>
#include <hip/hip_bf16.h>

#define NB 16
#define NN 1024
#define NP 1025
#define ND 24
#define N_ITERS 20

#define NORM_C  (-7.6246189861593985f)   // -log(2048)
#define LOGN_C  ( 6.9314718055994531f)   // log(1024)
#define LOG2E    1.4426950408889634f
#define LN2      0.6931471805599453f
#define MNORM    7.6246189861593985f     // -norm

// ---- ws layout (fast path): bf16 couplings in base-2 domain, no dustbin col
#define CP_ELEMS  ((size_t)NB * NP * NN)
#define U_OFF     (CP_ELEMS * 2)
#define V_OFF     (U_OFF + (size_t)NB * NP * 4)
#define WS_NEEDED (V_OFF + (size_t)NB * NP * 4)

__device__ __forceinline__ float e2(float x) { return __builtin_amdgcn_exp2f(x); }
__device__ __forceinline__ float blo(unsigned q){ return __uint_as_float(q << 16); }
__device__ __forceinline__ float bhi(unsigned q){ return __uint_as_float(q & 0xffff0000u); }
__device__ __forceinline__ unsigned f2b(float f){
  __hip_bfloat16 h = __float2bfloat16(f);
  return (unsigned)*reinterpret_cast<unsigned short*>(&h);
}

// ---------------------------------------------------------------------------
// couplings' = (log2e/sqrt(24)) * dsc0^T dsc1, bf16, [b][i<1025][j<1024]
// ---------------------------------------------------------------------------
__global__ __launch_bounds__(256) void scores_k(
    const float* __restrict__ d0, const float* __restrict__ d1,
    unsigned short* __restrict__ cp)
{
  __shared__ float As[ND][64];
  __shared__ float Bs[ND][64];
  const int b  = blockIdx.z;
  const int i0 = blockIdx.y * 64;
  const int j0 = blockIdx.x * 64;
  const int tid = threadIdx.x;
  const float* pa = d0 + b * ND * NN;
  const float* pb = d1 + b * ND * NN;
  for (int e = tid; e < ND * 64; e += 256) {
    int dd = e >> 6, cc = e & 63;
    As[dd][cc] = pa[dd * NN + i0 + cc];
    Bs[dd][cc] = pb[dd * NN + j0 + cc];
  }
  __syncthreads();
  const int tx = tid & 15, ty = tid >> 4;
  float acc[4][4] = {};
  #pragma unroll
  for (int dd = 0; dd < ND; ++dd) {
    float a[4], bb[4];
    #pragma unroll
    for (int r = 0; r < 4; ++r) a[r]  = As[dd][ty * 4 + r];
    #pragma unroll
    for (int c = 0; c < 4; ++c) bb[c] = Bs[dd][tx * 4 + c];
    #pragma unroll
    for (int r = 0; r < 4; ++r)
      #pragma unroll
      for (int c = 0; c < 4; ++c)
        acc[r][c] = fmaf(a[r], bb[c], acc[r][c]);
  }
  const float sc = 0.20412414523193154f * LOG2E;   // log2e / sqrt(24)
  #pragma unroll
  for (int r = 0; r < 4; ++r) {
    size_t base = ((size_t)b * NP + (i0 + ty * 4 + r)) * NN + j0 + tx * 4;
    uint2 pk;
    pk.x = f2b(acc[r][0] * sc) | (f2b(acc[r][1] * sc) << 16);
    pk.y = f2b(acc[r][2] * sc) | (f2b(acc[r][3] * sc) << 16);
    *reinterpret_cast<uint2*>(cp + base) = pk;
  }
}

// dustbin row (i = 1024) = alpha * log2e
__global__ __launch_bounds__(256) void init_k(
    unsigned short* __restrict__ cp, const float* __restrict__ alpha_p)
{
  const unsigned short a16 = (unsigned short)f2b((*alpha_p) * LOG2E);
  int idx = blockIdx.x * 256 + threadIdx.x;   // 16 * 1024
  int b = idx >> 10, j = idx & 1023;
  cp[((size_t)b * NP + NN) * NN + j] = a16;
}

// ---------------------------------------------------------------------------
// row pass: U[i] = lmu2 - log2( sum_j 2^(c'+V_j) + 2^(a2+V[1024]) )
// 1D grid 2064: b = bid&15 (XCD pin), rblk = bid>>4; 8 waves = 8 rows/block
// ---------------------------------------------------------------------------
__global__ __launch_bounds__(512) void row_k(
    const unsigned short* __restrict__ cp,
    const float* __restrict__ Varr, const float* __restrict__ alpha_p,
    float* __restrict__ Uarr)
{
  __shared__ float Vl[NP];
  const int bid = blockIdx.x;
  const int b = bid & 15;
  const int rblk = bid >> 4;
  const int tid = threadIdx.x;
  const float* V = Varr + b * NP;
  for (int k = tid; k < NP; k += 512) Vl[k] = V[k];
  __syncthreads();
  const int w = tid >> 6, lane = tid & 63;
  const int i = rblk * 8 + w;
  if (i >= NP) return;
  const float dust = e2((*alpha_p) * LOG2E + Vl[NN]);
  const unsigned short* crow = cp + ((size_t)b * NP + i) * NN;
  float s0 = 0.f, s1 = 0.f;
  #pragma unroll
  for (int itr = 0; itr < 2; ++itr) {
    int j = itr * 512 + lane * 8;
    uint4 q = *reinterpret_cast<const uint4*>(crow + j);
    float4 va = *reinterpret_cast<const float4*>(&Vl[j]);
    float4 vb = *reinterpret_cast<const float4*>(&Vl[j + 4]);
    s0 += e2(blo(q.x) + va.x);
    s1 += e2(bhi(q.x) + va.y);
    s0 += e2(blo(q.y) + va.z);
    s1 += e2(bhi(q.y) + va.w);
    s0 += e2(blo(q.z) + vb.x);
    s1 += e2(bhi(q.z) + vb.y);
    s0 += e2(blo(q.w) + vb.z);
    s1 += e2(bhi(q.w) + vb.w);
  }
  float s = s0 + s1;
  #pragma unroll
  for (int off = 32; off; off >>= 1)
    s += __shfl_xor(s, off, 64);
  if (lane == 0) {
    s += dust;
    Uarr[b * NP + i] = ((i == NN) ? -1.0f : -11.0f) - __log2f(s);
  }
}

// ---------------------------------------------------------------------------
// col pass: V[j] = -11 - log2( sum_i 2^(c'+U_i) ); V[1024] analytic
// 1D grid 256: b = bid&15 (XCD pin), j0 = (bid>>4)*64; 16 waves x 64 rows
// ---------------------------------------------------------------------------
__global__ __launch_bounds__(1024) void col_k(
    const unsigned short* __restrict__ cp,
    const float* __restrict__ Uarr, const float* __restrict__ alpha_p,
    float* __restrict__ Varr)
{
  __shared__ float Ul[NP];
  __shared__ float SS[16][64];
  const int bid = blockIdx.x;
  const int b = bid & 15;
  const int j0 = (bid >> 4) * 64;
  const int tid = threadIdx.x;
  const float* U = Uarr + b * NP;
  for (int k = tid; k < NP; k += 1024) Ul[k] = U[k];
  __syncthreads();
  const int w = tid >> 6, lane = tid & 63;
  const unsigned short* pc = cp + (size_t)b * NP * NN + j0 + lane;
  const int i0 = w * 64;
  float s0 = 0.f, s1 = 0.f;
  #pragma unroll 4
  for (int ii = i0; ii < i0 + 64; ii += 4) {
    float4 uq = *reinterpret_cast<const float4*>(&Ul[ii]);
    unsigned c0 = pc[(size_t)(ii + 0) * NN];
    unsigned c1 = pc[(size_t)(ii + 1) * NN];
    unsigned c2 = pc[(size_t)(ii + 2) * NN];
    unsigned c3 = pc[(size_t)(ii + 3) * NN];
    s0 += e2(blo(c0) + uq.x);
    s1 += e2(blo(c1) + uq.y);
    s0 += e2(blo(c2) + uq.z);
    s1 += e2(blo(c3) + uq.w);
  }
  if (w == 15)   // dustbin row 1024 (stored in matrix)
    s0 += e2(blo((unsigned)pc[(size_t)NN * NN]) + Ul[NN]);
  SS[w][lane] = s0 + s1;
  // dustbin column partial (one wave of the j0==0 block), overlaps main work
  float sd = 0.f;
  if (j0 == 0 && w == 1) {
    const float a2 = (*alpha_p) * LOG2E;
    for (int i = lane; i < NP; i += 64) sd += e2(a2 + Ul[i]);
    #pragma unroll
    for (int off = 32; off; off >>= 1) sd += __shfl_xor(sd, off, 64);
  }
  __syncthreads();
  if (tid < 64) {
    float s = 0.f;
    #pragma unroll
    for (int r = 0; r < 16; ++r) s += SS[r][tid];
    Varr[b * NP + j0 + tid] = -11.0f - __log2f(s);
  }
  if (j0 == 0 && w == 1 && lane == 0)
    Varr[b * NP + NN] = -1.0f - __log2f(sd);
}

// ---------------------------------------------------------------------------
// final: Z = (c' + U + V) * ln2 + 7.6246; dustbin col analytic; f32 out
// ---------------------------------------------------------------------------
__global__ __launch_bounds__(512) void final_k(
    const unsigned short* __restrict__ cp,
    const float* __restrict__ Uarr, const float* __restrict__ Varr,
    const float* __restrict__ alpha_p, float* __restrict__ Z)
{
  __shared__ float Vl[NP];
  const int bid = blockIdx.x;
  const int b = bid & 15;
  const int rblk = bid >> 4;
  const int tid = threadIdx.x;
  for (int k = tid; k < NP; k += 512) Vl[k] = Varr[b * NP + k];
  __syncthreads();
  const int w = tid >> 6, lane = tid & 63;
  const int i = rblk * 8 + w;
  if (i >= NP) return;
  const float ui = Uarr[b * NP + i];
  const unsigned short* crow = cp + ((size_t)b * NP + i) * NN;
  float* zrow = Z + ((size_t)b * NP + i) * NP;
  #pragma unroll
  for (int itr = 0; itr < 2; ++itr) {
    int j = itr * 512 + lane * 8;
    uint4 q = *reinterpret_cast<const uint4*>(crow + j);
    float4 va = *reinterpret_cast<const float4*>(&Vl[j]);
    float4 vb = *reinterpret_cast<const float4*>(&Vl[j + 4]);
    float4 z0, z1;
    z0.x = fmaf(blo(q.x) + ui + va.x, LN2, MNORM);
    z0.y = fmaf(bhi(q.x) + ui + va.y, LN2, MNORM);
    z0.z = fmaf(blo(q.y) + ui + va.z, LN2, MNORM);
    z0.w = fmaf(bhi(q.y) + ui + va.w, LN2, MNORM);
    z1.x = fmaf(blo(q.z) + ui + vb.x, LN2, MNORM);
    z1.y = fmaf(bhi(q.z) + ui + vb.y, LN2, MNORM);
    z1.z = fmaf(blo(q.w) + ui + vb.z, LN2, MNORM);
    z1.w = fmaf(bhi(q.w) + ui + vb.w, LN2, MNORM);
    *reinterpret_cast<float4*>(zrow + j) = z0;
    *reinterpret_cast<float4*>(zrow + j + 4) = z1;
  }
  if (lane == 0)
    zrow[NN] = fmaf((*alpha_p) * LOG2E + ui + Vl[NN], LN2, MNORM);
}

// ===========================================================================
// Fallback path (round-2 verified, f32 in d_out) if ws too small
// ===========================================================================
__global__ __launch_bounds__(256) void fb_scores(
    const float* __restrict__ d0, const float* __restrict__ d1, float* __restrict__ C)
{
  __shared__ float As[ND][64];
  __shared__ float Bs[ND][64];
  const int b  = blockIdx.z;
  const int n0 = blockIdx.y * 64;
  const int m0 = blockIdx.x * 64;
  const int tid = threadIdx.x;
  const float* pa = d0 + b * ND * NN;
  const float* pb = d1 + b * ND * NN;
  for (int e = tid; e < ND * 64; e += 256) {
    int dd = e >> 6, cc = e & 63;
    As[dd][cc] = pa[dd * NN + n0 + cc];
    Bs[dd][cc] = pb[dd * NN + m0 + cc];
  }
  __syncthreads();
  const int tx = tid & 15, ty = tid >> 4;
  float acc[4][4] = {};
  #pragma unroll
  for (int dd = 0; dd < ND; ++dd) {
    float a[4], bb[4];
    #pragma unroll
    for (int r = 0; r < 4; ++r) a[r]  = As[dd][ty * 4 + r];
    #pragma unroll
    for (int c = 0; c < 4; ++c) bb[c] = Bs[dd][tx * 4 + c];
    #pragma unroll
    for (int r = 0; r < 4; ++r)
      #pragma unroll
      for (int c = 0; c < 4; ++c)
        acc[r][c] = fmaf(a[r], bb[c], acc[r][c]);
  }
  const float sc = 0.20412414523193154f;
  #pragma unroll
  for (int r = 0; r < 4; ++r) {
    size_t base = ((size_t)b * NP + n0 + ty * 4 + r) * NP + m0 + tx * 4;
    #pragma unroll
    for (int c = 0; c < 4; ++c)
      C[base + c] = acc[r][c] * sc;
  }
}
__global__ __launch_bounds__(256) void fb_init(
    float* __restrict__ C, float* __restrict__ v, const float* __restrict__ alpha_p)
{
  const float alpha = *alpha_p;
  int idx = blockIdx.x * 256 + threadIdx.x;
  if (idx >= NB * NP) return;
  int b = idx / NP, x = idx - b * NP;
  C[((size_t)b * NP + NN) * NP + x] = alpha;
  C[((size_t)b * NP + x) * NP + NN] = alpha;
  v[idx] = 0.f;
}
__global__ __launch_bounds__(256) void fb_row(
    const float* __restrict__ C, const float* __restrict__ v, float* __restrict__ u)
{
  const int wid  = (blockIdx.x * 256 + threadIdx.x) >> 6;
  const int lane = threadIdx.x & 63;
  const int b = wid / NP, i = wid - b * NP;
  const float* crow = C + ((size_t)b * NP + i) * NP;
  const float* vb = v + b * NP;
  float s = 0.f;
  #pragma unroll
  for (int k = 0; k < 17; ++k) {
    int j = k * 64 + lane;
    if (j < NP) s += __expf(crow[j] + vb[j]);
  }
  #pragma unroll
  for (int off = 32; off; off >>= 1) s += __shfl_xor(s, off, 64);
  if (lane == 0) {
    float log_mu = NORM_C + (i == NN ? LOGN_C : 0.f);
    u[b * NP + i] = log_mu - __logf(s);
  }
}
__global__ __launch_bounds__(256) void fb_col(
    const float* __restrict__ C, const float* __restrict__ u, float* __restrict__ v)
{
  const int b  = blockIdx.y;
  const int tx = threadIdx.x & 31, ty = threadIdx.x >> 5;
  const int j  = blockIdx.x * 32 + tx;
  const bool valid = (j < NP);
  const float* cbp = C + (size_t)b * NP * NP;
  const float* ub = u + b * NP;
  float s = 0.f;
  if (valid) {
    #pragma unroll 4
    for (int i = ty; i < NP; i += 8)
      s += __expf(cbp[(size_t)i * NP + j] + ub[i]);
  }
  __shared__ float ss[8][32];
  ss[ty][tx] = s;
  __syncthreads();
  if (ty == 0 && valid) {
    #pragma unroll
    for (int r = 1; r < 8; ++r) s += ss[r][tx];
    float log_nu = NORM_C + (j == NN ? LOGN_C : 0.f);
    v[b * NP + j] = log_nu - __logf(s);
  }
}
__global__ __launch_bounds__(256) void fb_final(
    float* __restrict__ C, const float* __restrict__ u, const float* __restrict__ v)
{
  int idx = blockIdx.x * 256 + threadIdx.x;
  const int total = NB * NP * NP;
  if (idx >= total) return;
  int b = idx / (NP * NP);
  int rem = idx - b * (NP * NP);
  int i = rem / NP, j = rem - i * NP;
  C[idx] = C[idx] + u[b * NP + i] + v[b * NP + j] - NORM_C;
}

extern "C" void kernel_launch(void* const* d_in, const int* in_sizes, int n_in,
                              void* d_out, int out_size, void* d_ws, size_t ws_size,
                              hipStream_t stream) {
  const float* d0    = (const float*)d_in[0];
  const float* d1    = (const float*)d_in[1];
  const float* alpha = (const float*)d_in[2];
  float* Z = (float*)d_out;

  if (ws_size >= WS_NEEDED) {
    unsigned short* cpp = (unsigned short*)d_ws;
    float* U = (float*)((char*)d_ws + U_OFF);
    float* V = (float*)((char*)d_ws + V_OFF);
    hipMemsetAsync(V, 0, (size_t)NB * NP * 4, stream);   // V = 0 each call

    scores_k<<<dim3(16, 16, NB), 256, 0, stream>>>(d0, d1, cpp);
    init_k<<<64, 256, 0, stream>>>(cpp, alpha);

    for (int it = 0; it < N_ITERS; ++it) {
      row_k<<<2064, 512, 0, stream>>>(cpp, V, alpha, U);
      col_k<<<256, 1024, 0, stream>>>(cpp, U, alpha, V);
    }
    final_k<<<2064, 512, 0, stream>>>(cpp, U, V, alpha, Z);
  } else {
    float* v = (float*)d_ws;
    float* u = v + NB * NP;
    fb_scores<<<dim3(NN / 64, NN / 64, NB), 256, 0, stream>>>(d0, d1, Z);
    fb_init<<<(NB * NP + 255) / 256, 256, 0, stream>>>(Z, v, alpha);
    for (int it = 0; it < N_ITERS; ++it) {
      fb_row<<<(NB * NP) / 4, 256, 0, stream>>>(Z, v, u);
      fb_col<<<dim3((NP + 31) / 32, NB), 256, 0, stream>>>(Z, u, v);
    }
    fb_final<<<(NB * NP * NP + 255) / 256, 256, 0, stream>>>(Z, u, v);
  }
}